// Round 14
// baseline (807.385 us; speedup 1.0000x reference)
//
#include <hip/hip_runtime.h>

typedef short short8 __attribute__((ext_vector_type(8)));
typedef __bf16 bf16x8 __attribute__((ext_vector_type(8)));
typedef float floatx4 __attribute__((ext_vector_type(4)));

__device__ __forceinline__ float make_pow2(int e) {
  return __builtin_bit_cast(float, (unsigned)((e + 127) << 23));
}

// Raw barrier: drains LDS ops only (global loads are all to-register; ordinary
// register dependencies handle their waits).
__device__ __forceinline__ void barrier_lgkm() {
  asm volatile("s_waitcnt lgkmcnt(0)" ::: "memory");
  __builtin_amdgcn_sched_barrier(0);
  __builtin_amdgcn_s_barrier();
  asm volatile("" ::: "memory");
  __builtin_amdgcn_sched_barrier(0);
}

// ---------------- Phase 1: quantize weights -> bf16 FRAGMENT-ORDER blob ----------------
// Blob layout: [ct(16)][kb(18)][ks(2)][lane(64)][j(8)] bf16 = mfma src0 frag order.
__global__ void quant_w_kernel(const float* __restrict__ w, unsigned short* __restrict__ qw) {
  int b = blockIdx.x;                 // 0..287
  int ct = b / 18, kb = b - ct * 18;
  int L = threadIdx.x;                // 0..63
  int co = ct * 16 + (L & 15);
  int kq = L >> 4;                    // 0..3
  const float* wr = w + co * 1152 + kb * 64 + kq * 8;
  float v[16];
  float a = 0.f;
  #pragma unroll
  for (int ks = 0; ks < 2; ++ks)
    #pragma unroll
    for (int j = 0; j < 8; ++j) {
      float t = wr[ks * 32 + j];
      v[ks * 8 + j] = t;
      a = fmaxf(a, fabsf(t));
    }
  a = fmaxf(a, __shfl_xor(a, 16));
  a = fmaxf(a, __shfl_xor(a, 32));
  short8 q0 = (short8)0, q1 = (short8)0;
  if (a > 0.f) {
    int e = (int)((__builtin_bit_cast(unsigned, a) >> 23) & 0xffu) - 127;
    if (e < -126) e = -126;
    float inv = make_pow2(6 - e);
    float s   = make_pow2(e - 6);
    #pragma unroll
    for (int u = 0; u < 16; ++u) {
      float r = rintf(v[u] * inv);
      r = fminf(fmaxf(r, -128.f), 127.f);
      float qq = r * s;
      unsigned short hb = (unsigned short)(__builtin_bit_cast(unsigned, qq) >> 16);
      if (u < 8) q0[u] = (short)hb; else q1[u - 8] = (short)hb;
    }
  }
  unsigned short* dst = qw + (size_t)(ct * 18 + kb) * 1024;
  *(short8*)(dst + L * 8) = q0;          // ks = 0
  *(short8*)(dst + 512 + L * 8) = q1;    // ks = 1
}

// ---------------- Phase 2: fused im2col + BFP-quantize + GEMM ----------------
// M=100352, N=256, K=1152. BM=64, BN=256. 512 thr = 8 waves in a 2x4 grid:
// wm=wave>>2 owns rows wm*32..+31, wn=wave&3 owns cols wn*64..+63, acc[2][4].
// (vs r8's 1x8 grid this HALVES the per-wave A-fragment ds_reads — the top
// LDS-pipe load — at the cost of 2x B global loads, which are L2-resident.)
// Producer side identical to r8: scalarized gather (wave-uniform k), pmax LDS
// reduce, 2-kb superphase with one lgkm barrier, 4-slot As/pmax rotation.
__global__ __launch_bounds__(512, 4) void conv_bfp_kernel(
    const float* __restrict__ in, const unsigned short* __restrict__ qw,
    const float* __restrict__ bias, float* __restrict__ out) {
  __shared__ unsigned short As[4][64 * 64];    // 32 KB, 4-slot rotation
  __shared__ float pmax[4][8][64];             // 8 KB  [slot][wave][row]

  const int bid = blockIdx.x;
  const int mt = (bid & 7) * 196 + (bid >> 3);   // XCD-chunked swizzle (1568 = 8*196)
  const int t = threadIdx.x;
  const int lane = t & 63;
  const int wave = __builtin_amdgcn_readfirstlane(t >> 6);
  const int wm = wave >> 2;                      // M-half: rows wm*32..+31
  const int wn = wave & 3;                       // N-quarter: cols wn*64..+63

  // ---- pixel geometry (A row = lane) ----
  const unsigned m = mt * 64u + lane;
  const unsigned nimg = m / 3136u;
  const unsigned py = m - nimg * 3136u;
  const int y = (int)(py / 56u);
  const int x = (int)(py - (unsigned)y * 56u);
  const int vbase = (int)((nimg * 401408u + (unsigned)y * 56u + (unsigned)x) * 4u);
  int vm = 0;
  #pragma unroll
  for (int i = 0; i < 3; ++i)
    #pragma unroll
    for (int j = 0; j < 3; ++j)
      if ((unsigned)(y + i - 1) < 56u && (unsigned)(x + j - 1) < 56u)
        vm |= 1 << (i * 3 + j);

  const int lr = lane & 15;
  const int lk = (lane >> 4) << 4;
  const int swz = (lr & 7) << 4;

  floatx4 acc[2][4] = {};

  auto gather = [&](float (&av)[8], int kb) {
    const int k0 = __builtin_amdgcn_readfirstlane(kb * 64 + wave * 8);
    #pragma unroll
    for (int u = 0; u < 8; ++u) {
      int k = k0 + u;                          // scalar
      int c = (int)((unsigned)k / 9u);
      int ij = k - c * 9;
      int soff = c * 3136 + (ij / 3) * 56 + (ij % 3) - 57;
      const char* pk = (const char*)in + (ptrdiff_t)soff * 4;
      float v = 0.f;
      if ((vm >> ij) & 1)
        v = *(const float*)(pk + vbase);       // global_load_dword v, vbase, s[pk]
      av[u] = v;
    }
  };

  auto loadB = [&](bf16x8 (&bq)[2][4], int kb) {   // [ks][fn], 8x global dwordx4
    #pragma unroll
    for (int ks = 0; ks < 2; ++ks)
      #pragma unroll
      for (int fn = 0; fn < 4; ++fn) {
        int ct = wn * 4 + fn;
        bq[ks][fn] = __builtin_bit_cast(bf16x8, *(const short8*)(
            (const char*)qw + ((size_t)((ct * 18 + kb) * 2 + ks) * 64 + lane) * 16));
      }
  };

  auto lmax_store = [&](float (&av)[8], int kb) {
    float lm = 0.f;
    #pragma unroll
    for (int u = 0; u < 8; ++u) lm = fmaxf(lm, fabsf(av[u]));
    pmax[kb & 3][wave][lane] = lm;
  };

  auto quantWrite = [&](float (&av)[8], int kb) {  // -> As[kb&3], reads pmax[kb&3]
    const float* pb = &pmax[kb & 3][0][lane];
    float ma = 0.f;
    #pragma unroll
    for (int j = 0; j < 8; ++j) ma = fmaxf(ma, pb[j * 64]);
    short8 aq = (short8)0;
    if (ma > 0.f) {
      int e = (int)((__builtin_bit_cast(unsigned, ma) >> 23) & 0xffu) - 127;
      if (e < -126) e = -126;
      float inv = make_pow2(6 - e);
      float s   = make_pow2(e - 6);
      #pragma unroll
      for (int u = 0; u < 8; ++u) {
        float r = fminf(rintf(av[u] * inv), 127.f);  // lower clamp never binds
        float q = r * s;
        aq[u] = (short)(unsigned short)(__builtin_bit_cast(unsigned, q) >> 16);
      }
    }
    char* arow = (char*)As[kb & 3] + lane * 128;
    *(short8*)(arow + ((wave * 16) ^ ((lane & 7) << 4))) = aq;
  };

  auto mfmaBlk = [&](bf16x8 (&bq)[2][4], int kb) {  // reads As[kb&3], rows wm*32..
    const char* abase = (const char*)As[kb & 3] + wm * 32 * 128;
    __builtin_amdgcn_s_setprio(1);
    #pragma unroll
    for (int ks = 0; ks < 2; ++ks) {
      const int kbyte = (ks * 64 + lk) ^ swz;
      #pragma unroll
      for (int fm = 0; fm < 2; ++fm) {
        bf16x8 af = __builtin_bit_cast(bf16x8,
            *(const short8*)(abase + (fm * 16 + lr) * 128 + kbyte));
        #pragma unroll
        for (int fn = 0; fn < 4; ++fn)
          acc[fm][fn] = __builtin_amdgcn_mfma_f32_16x16x32_bf16(bq[ks][fn], af, acc[fm][fn], 0, 0, 0);
      }
    }
    __builtin_amdgcn_s_setprio(0);
  };

  // Superphase: one barrier per 2 kb. q0/q1 hold gathered kb+2/kb+3;
  // g0/g1 receive kb+4/kb+5.
  auto superp = [&](int kb, float (&q0)[8], float (&q1)[8],
                    float (&g0)[8], float (&g1)[8]) {
    barrier_lgkm();                // As[kb&3],[kb+1&3] + pmax[(kb+2)&3],[(kb+3)&3] visible
    bf16x8 bq[2][4], bq2[2][4];
    loadB(bq, kb);
    if (kb + 2 < 18) { quantWrite(q0, kb + 2); quantWrite(q1, kb + 3); }
    if (kb + 4 < 18) { gather(g0, kb + 4); gather(g1, kb + 5); }
    loadB(bq2, kb + 1);            // covered by mfma(kb)
    mfmaBlk(bq, kb);
    if (kb + 4 < 18) { lmax_store(g0, kb + 4); lmax_store(g1, kb + 5); }
    mfmaBlk(bq2, kb + 1);
  };

  float gA[8], gB[8], gC[8], gD[8];

  // ---- prologue: fill pmax 0..3 and As 0,1 ----
  gather(gA, 0); gather(gB, 1); gather(gC, 2); gather(gD, 3);
  lmax_store(gA, 0); lmax_store(gB, 1); lmax_store(gC, 2); lmax_store(gD, 3);
  barrier_lgkm();                  // pmax 0..3 visible
  quantWrite(gA, 0); quantWrite(gB, 1);   // As0, As1  (gA,gB free)

  #pragma unroll 1
  for (int kb = 0; kb < 16; kb += 4) {
    superp(kb,     gC, gD, gA, gB);   // quant kb+2,kb+3; gather kb+4,kb+5
    superp(kb + 2, gA, gB, gC, gD);
  }
  superp(16, gC, gD, gA, gB);         // mfma 16,17 only (guards skip the rest)

  // ---- epilogue: D[co][pix]; 3136 = 49*64 so the 64-row tile is one image ----
  const unsigned ni = (mt * 64u) / 3136u;
  const unsigned pp0 = mt * 64u - ni * 3136u;
  float* obase = out + (size_t)ni * 802816u + pp0;
  const int cg = (lane >> 4) << 2;
  #pragma unroll
  for (int fn = 0; fn < 4; ++fn) {
    floatx4 bv = *(const floatx4*)&bias[wn * 64 + fn * 16 + cg];
    #pragma unroll
    for (int r = 0; r < 4; ++r) {
      int co = wn * 64 + fn * 16 + cg + r;
      float* orow = obase + (size_t)co * 3136u;
      #pragma unroll
      for (int fm = 0; fm < 2; ++fm)
        orow[wm * 32 + fm * 16 + lr] = acc[fm][fn][r] + bv[r];
    }
  }
}

extern "C" void kernel_launch(void* const* d_in, const int* in_sizes, int n_in,
                              void* d_out, int out_size, void* d_ws, size_t ws_size,
                              hipStream_t stream) {
  const float* in   = (const float*)d_in[0];
  const float* w    = (const float*)d_in[1];
  const float* bias = (const float*)d_in[2];
  float* out = (float*)d_out;
  unsigned short* qw = (unsigned short*)d_ws;   // 16*18*1024 ushort = 589824 B

  quant_w_kernel<<<288, 64, 0, stream>>>(w, qw);
  conv_bfp_kernel<<<1568, 512, 0, stream>>>(in, qw, bias, out);
}

// Round 15
// 143.761 us; speedup vs baseline: 5.6162x; 5.6162x over previous
//
#include <hip/hip_runtime.h>

typedef short short8 __attribute__((ext_vector_type(8)));
typedef __bf16 bf16x8 __attribute__((ext_vector_type(8)));
typedef float floatx4 __attribute__((ext_vector_type(4)));

__device__ __forceinline__ float make_pow2(int e) {
  return __builtin_bit_cast(float, (unsigned)((e + 127) << 23));
}

// Raw barrier: drains LDS ops only (global loads are all to-register; ordinary
// register dependencies handle their waits).
__device__ __forceinline__ void barrier_lgkm() {
  asm volatile("s_waitcnt lgkmcnt(0)" ::: "memory");
  __builtin_amdgcn_sched_barrier(0);
  __builtin_amdgcn_s_barrier();
  asm volatile("" ::: "memory");
  __builtin_amdgcn_sched_barrier(0);
}

// ---------------- Phase 1: quantize weights -> bf16 FRAGMENT-ORDER blob ----------------
// Blob layout: [ct(16)][kb(18)][ks(2)][lane(64)][j(8)] bf16 = mfma src0 frag order.
__global__ void quant_w_kernel(const float* __restrict__ w, unsigned short* __restrict__ qw) {
  int b = blockIdx.x;                 // 0..287
  int ct = b / 18, kb = b - ct * 18;
  int L = threadIdx.x;                // 0..63
  int co = ct * 16 + (L & 15);
  int kq = L >> 4;                    // 0..3
  const float* wr = w + co * 1152 + kb * 64 + kq * 8;
  float v[16];
  float a = 0.f;
  #pragma unroll
  for (int ks = 0; ks < 2; ++ks)
    #pragma unroll
    for (int j = 0; j < 8; ++j) {
      float t = wr[ks * 32 + j];
      v[ks * 8 + j] = t;
      a = fmaxf(a, fabsf(t));
    }
  a = fmaxf(a, __shfl_xor(a, 16));
  a = fmaxf(a, __shfl_xor(a, 32));
  short8 q0 = (short8)0, q1 = (short8)0;
  if (a > 0.f) {
    int e = (int)((__builtin_bit_cast(unsigned, a) >> 23) & 0xffu) - 127;
    if (e < -126) e = -126;
    float inv = make_pow2(6 - e);
    float s   = make_pow2(e - 6);
    #pragma unroll
    for (int u = 0; u < 16; ++u) {
      float r = rintf(v[u] * inv);
      r = fminf(fmaxf(r, -128.f), 127.f);
      float qq = r * s;
      unsigned short hb = (unsigned short)(__builtin_bit_cast(unsigned, qq) >> 16);
      if (u < 8) q0[u] = (short)hb; else q1[u - 8] = (short)hb;
    }
  }
  unsigned short* dst = qw + (size_t)(ct * 18 + kb) * 1024;
  *(short8*)(dst + L * 8) = q0;          // ks = 0
  *(short8*)(dst + 512 + L * 8) = q1;    // ks = 1
}

// ---------------- Phase 2: fused im2col + BFP-quantize + GEMM ----------------
// M=100352, N=256, K=1152. BM=64, BN=256. 512 thr = 8 waves in a 2x4 grid:
// wm=wave>>2 owns rows wm*32..+31, wn=wave&3 owns cols wn*64..+63, acc[2][4].
// Halves per-wave A-fragment ds_reads vs the 1x8 grid (top LDS-pipe load);
// B comes from the L2-resident fragment blob, SINGLE-buffered (one bq[2][4]
// reused for kb and kb+1) so the live set stays ~95 regs — no spill (r14 bug).
// Producer identical to r8: scalarized gather, pmax LDS reduce, 2-kb superphase
// with one lgkm barrier, 4-slot As/pmax rotation.
__global__ __launch_bounds__(512, 4) void conv_bfp_kernel(
    const float* __restrict__ in, const unsigned short* __restrict__ qw,
    const float* __restrict__ bias, float* __restrict__ out) {
  __shared__ unsigned short As[4][64 * 64];    // 32 KB, 4-slot rotation
  __shared__ float pmax[4][8][64];             // 8 KB  [slot][wave][row]

  const int bid = blockIdx.x;
  const int mt = (bid & 7) * 196 + (bid >> 3);   // XCD-chunked swizzle (1568 = 8*196)
  const int t = threadIdx.x;
  const int lane = t & 63;
  const int wave = __builtin_amdgcn_readfirstlane(t >> 6);
  const int wm = wave >> 2;                      // M-half: rows wm*32..+31
  const int wn = wave & 3;                       // N-quarter: cols wn*64..+63

  // ---- pixel geometry (A row = lane) ----
  const unsigned m = mt * 64u + lane;
  const unsigned nimg = m / 3136u;
  const unsigned py = m - nimg * 3136u;
  const int y = (int)(py / 56u);
  const int x = (int)(py - (unsigned)y * 56u);
  const int vbase = (int)((nimg * 401408u + (unsigned)y * 56u + (unsigned)x) * 4u);
  int vm = 0;
  #pragma unroll
  for (int i = 0; i < 3; ++i)
    #pragma unroll
    for (int j = 0; j < 3; ++j)
      if ((unsigned)(y + i - 1) < 56u && (unsigned)(x + j - 1) < 56u)
        vm |= 1 << (i * 3 + j);

  const int lr = lane & 15;
  const int lk = (lane >> 4) << 4;
  const int swz = (lr & 7) << 4;

  floatx4 acc[2][4] = {};

  auto gather = [&](float (&av)[8], int kb) {
    const int k0 = __builtin_amdgcn_readfirstlane(kb * 64 + wave * 8);
    #pragma unroll
    for (int u = 0; u < 8; ++u) {
      int k = k0 + u;                          // scalar
      int c = (int)((unsigned)k / 9u);
      int ij = k - c * 9;
      int soff = c * 3136 + (ij / 3) * 56 + (ij % 3) - 57;
      const char* pk = (const char*)in + (ptrdiff_t)soff * 4;
      float v = 0.f;
      if ((vm >> ij) & 1)
        v = *(const float*)(pk + vbase);       // global_load_dword v, vbase, s[pk]
      av[u] = v;
    }
  };

  auto loadB = [&](bf16x8 (&bq)[2][4], int kb) {   // [ks][fn], 8x global dwordx4
    #pragma unroll
    for (int ks = 0; ks < 2; ++ks)
      #pragma unroll
      for (int fn = 0; fn < 4; ++fn) {
        int ct = wn * 4 + fn;
        bq[ks][fn] = __builtin_bit_cast(bf16x8, *(const short8*)(
            (const char*)qw + ((size_t)((ct * 18 + kb) * 2 + ks) * 64 + lane) * 16));
      }
  };

  auto lmax_store = [&](float (&av)[8], int kb) {
    float lm = 0.f;
    #pragma unroll
    for (int u = 0; u < 8; ++u) lm = fmaxf(lm, fabsf(av[u]));
    pmax[kb & 3][wave][lane] = lm;
  };

  auto quantWrite = [&](float (&av)[8], int kb) {  // -> As[kb&3], reads pmax[kb&3]
    const float* pb = &pmax[kb & 3][0][lane];
    float ma = 0.f;
    #pragma unroll
    for (int j = 0; j < 8; ++j) ma = fmaxf(ma, pb[j * 64]);
    short8 aq = (short8)0;
    if (ma > 0.f) {
      int e = (int)((__builtin_bit_cast(unsigned, ma) >> 23) & 0xffu) - 127;
      if (e < -126) e = -126;
      float inv = make_pow2(6 - e);
      float s   = make_pow2(e - 6);
      #pragma unroll
      for (int u = 0; u < 8; ++u) {
        float r = fminf(rintf(av[u] * inv), 127.f);  // lower clamp never binds
        float q = r * s;
        aq[u] = (short)(unsigned short)(__builtin_bit_cast(unsigned, q) >> 16);
      }
    }
    char* arow = (char*)As[kb & 3] + lane * 128;
    *(short8*)(arow + ((wave * 16) ^ ((lane & 7) << 4))) = aq;
  };

  auto mfmaBlk = [&](bf16x8 (&bq)[2][4], int kb) {  // reads As[kb&3], rows wm*32..
    const char* abase = (const char*)As[kb & 3] + wm * 32 * 128;
    __builtin_amdgcn_s_setprio(1);
    #pragma unroll
    for (int ks = 0; ks < 2; ++ks) {
      const int kbyte = (ks * 64 + lk) ^ swz;
      #pragma unroll
      for (int fm = 0; fm < 2; ++fm) {
        bf16x8 af = __builtin_bit_cast(bf16x8,
            *(const short8*)(abase + (fm * 16 + lr) * 128 + kbyte));
        #pragma unroll
        for (int fn = 0; fn < 4; ++fn)
          acc[fm][fn] = __builtin_amdgcn_mfma_f32_16x16x32_bf16(bq[ks][fn], af, acc[fm][fn], 0, 0, 0);
      }
    }
    __builtin_amdgcn_s_setprio(0);
  };

  // Superphase: one barrier per 2 kb; SINGLE bq buffer reused for kb and kb+1.
  auto superp = [&](int kb, float (&q0)[8], float (&q1)[8],
                    float (&g0)[8], float (&g1)[8]) {
    barrier_lgkm();                // As[kb&3],[kb+1&3] + pmax[(kb+2)&3],[(kb+3)&3] visible
    bf16x8 bq[2][4];
    loadB(bq, kb);                 // L2 latency covered by quant+gather issue below
    if (kb + 2 < 18) { quantWrite(q0, kb + 2); quantWrite(q1, kb + 3); }
    if (kb + 4 < 18) { gather(g0, kb + 4); gather(g1, kb + 5); }
    mfmaBlk(bq, kb);
    loadB(bq, kb + 1);             // regs free after mfmaBlk; latency covered by lmax
    if (kb + 4 < 18) { lmax_store(g0, kb + 4); lmax_store(g1, kb + 5); }
    mfmaBlk(bq, kb + 1);
  };

  float gA[8], gB[8], gC[8], gD[8];

  // ---- prologue: fill pmax 0..3 and As 0,1 ----
  gather(gA, 0); gather(gB, 1); gather(gC, 2); gather(gD, 3);
  lmax_store(gA, 0); lmax_store(gB, 1); lmax_store(gC, 2); lmax_store(gD, 3);
  barrier_lgkm();                  // pmax 0..3 visible
  quantWrite(gA, 0); quantWrite(gB, 1);   // As0, As1  (gA,gB free)

  #pragma unroll 1
  for (int kb = 0; kb < 16; kb += 4) {
    superp(kb,     gC, gD, gA, gB);   // quant kb+2,kb+3; gather kb+4,kb+5
    superp(kb + 2, gA, gB, gC, gD);
  }
  superp(16, gC, gD, gA, gB);         // mfma 16,17 only (guards skip the rest)

  // ---- epilogue: D[co][pix]; 3136 = 49*64 so the 64-row tile is one image ----
  const unsigned ni = (mt * 64u) / 3136u;
  const unsigned pp0 = mt * 64u - ni * 3136u;
  float* obase = out + (size_t)ni * 802816u + pp0;
  const int cg = (lane >> 4) << 2;
  #pragma unroll
  for (int fn = 0; fn < 4; ++fn) {
    floatx4 bv = *(const floatx4*)&bias[wn * 64 + fn * 16 + cg];
    #pragma unroll
    for (int r = 0; r < 4; ++r) {
      int co = wn * 64 + fn * 16 + cg + r;
      float* orow = obase + (size_t)co * 3136u;
      #pragma unroll
      for (int fm = 0; fm < 2; ++fm)
        orow[wm * 32 + fm * 16 + lr] = acc[fm][fn][r] + bv[r];
    }
  }
}

extern "C" void kernel_launch(void* const* d_in, const int* in_sizes, int n_in,
                              void* d_out, int out_size, void* d_ws, size_t ws_size,
                              hipStream_t stream) {
  const float* in   = (const float*)d_in[0];
  const float* w    = (const float*)d_in[1];
  const float* bias = (const float*)d_in[2];
  float* out = (float*)d_out;
  unsigned short* qw = (unsigned short*)d_ws;   // 16*18*1024 ushort = 589824 B

  quant_w_kernel<<<288, 64, 0, stream>>>(w, qw);
  conv_bfp_kernel<<<1568, 512, 0, stream>>>(in, qw, bias, out);
}

// Round 16
// 139.425 us; speedup vs baseline: 5.7908x; 1.0311x over previous
//
#include <hip/hip_runtime.h>

typedef short short8 __attribute__((ext_vector_type(8)));
typedef __bf16 bf16x8 __attribute__((ext_vector_type(8)));
typedef float floatx4 __attribute__((ext_vector_type(4)));

__device__ __forceinline__ float make_pow2(int e) {
  return __builtin_bit_cast(float, (unsigned)((e + 127) << 23));
}

// Raw barrier: drains LDS ops only (global loads are all to-register; ordinary
// register dependencies handle their waits).
__device__ __forceinline__ void barrier_lgkm() {
  asm volatile("s_waitcnt lgkmcnt(0)" ::: "memory");
  __builtin_amdgcn_sched_barrier(0);
  __builtin_amdgcn_s_barrier();
  asm volatile("" ::: "memory");
  __builtin_amdgcn_sched_barrier(0);
}

// ---------------- Phase 1: quantize weights -> bf16 FRAGMENT-ORDER blob ----------------
// Blob layout: [ct(16)][kb(18)][ks(2)][lane(64)][j(8)] bf16 = mfma src0 frag order.
__global__ void quant_w_kernel(const float* __restrict__ w, unsigned short* __restrict__ qw) {
  int b = blockIdx.x;                 // 0..287
  int ct = b / 18, kb = b - ct * 18;
  int L = threadIdx.x;                // 0..63
  int co = ct * 16 + (L & 15);
  int kq = L >> 4;                    // 0..3
  const float* wr = w + co * 1152 + kb * 64 + kq * 8;
  float v[16];
  float a = 0.f;
  #pragma unroll
  for (int ks = 0; ks < 2; ++ks)
    #pragma unroll
    for (int j = 0; j < 8; ++j) {
      float t = wr[ks * 32 + j];
      v[ks * 8 + j] = t;
      a = fmaxf(a, fabsf(t));
    }
  a = fmaxf(a, __shfl_xor(a, 16));
  a = fmaxf(a, __shfl_xor(a, 32));
  short8 q0 = (short8)0, q1 = (short8)0;
  if (a > 0.f) {
    int e = (int)((__builtin_bit_cast(unsigned, a) >> 23) & 0xffu) - 127;
    if (e < -126) e = -126;
    float inv = make_pow2(6 - e);
    float s   = make_pow2(e - 6);
    #pragma unroll
    for (int u = 0; u < 16; ++u) {
      float r = rintf(v[u] * inv);
      r = fminf(fmaxf(r, -128.f), 127.f);
      float qq = r * s;
      unsigned short hb = (unsigned short)(__builtin_bit_cast(unsigned, qq) >> 16);
      if (u < 8) q0[u] = (short)hb; else q1[u - 8] = (short)hb;
    }
  }
  unsigned short* dst = qw + (size_t)(ct * 18 + kb) * 1024;
  *(short8*)(dst + L * 8) = q0;          // ks = 0
  *(short8*)(dst + 512 + L * 8) = q1;    // ks = 1
}

// ---------------- Phase 2: fused im2col + BFP-quantize + GEMM ----------------
// M=100352, N=256, K=1152. BM=32, BN=256. 256 thr = 4 waves (1x4 grid): wave
// owns cols wave*64..+63, all 32 rows; acc[2][4]. Per-wave schedule identical
// to r8 (2-kb superphase, one lgkm barrier, 4-slot As/pmax rotation, dbuf bq).
// vs r8: half the tile rows -> A ds_reads/wave halved (fm 4->2); B fragment
// loads doubled (fn 2->4, L2-resident); 4-wave barrier groups; 3136 blocks.
// Producer: wave w gathers k-slice [w*16 + (lane>>5)*8 .. +8) of row lane&31;
// 16-k max merged via shfl_xor(32); cross-wave max via pmax[slot][4][32].
__global__ __launch_bounds__(256, 3) void conv_bfp_kernel(
    const float* __restrict__ in, const unsigned short* __restrict__ qw,
    const float* __restrict__ bias, float* __restrict__ out) {
  __shared__ unsigned short As[4][32 * 64];    // 16 KB, 4-slot rotation
  __shared__ float pmax[4][4][32];             // 2 KB  [slot][wave][row]

  const int bid = blockIdx.x;
  const int mt = (bid & 7) * 392 + (bid >> 3);   // XCD-chunked swizzle (3136 = 8*392)
  const int t = threadIdx.x;
  const int lane = t & 63;
  const int wave = __builtin_amdgcn_readfirstlane(t >> 6);

  // ---- pixel geometry (A row = lane&31) ----
  const int prow = lane & 31;
  const unsigned m = mt * 32u + prow;
  const unsigned nimg = m / 3136u;
  const unsigned py = m - nimg * 3136u;
  const int y = (int)(py / 56u);
  const int x = (int)(py - (unsigned)y * 56u);
  const int vbase = (int)((nimg * 401408u + (unsigned)y * 56u + (unsigned)x) * 4u);
  int vm = 0;
  #pragma unroll
  for (int i = 0; i < 3; ++i)
    #pragma unroll
    for (int j = 0; j < 3; ++j)
      if ((unsigned)(y + i - 1) < 56u && (unsigned)(x + j - 1) < 56u)
        vm |= 1 << (i * 3 + j);

  const int lr = lane & 15;
  const int lk = (lane >> 4) << 4;
  const int swz = (lr & 7) << 4;
  const int khalf = lane >> 5;                   // which 8-k half of the wave's 16-k slice

  floatx4 acc[2][4] = {};

  auto gather = [&](float (&av)[8], int kb) {
    const int k0 = __builtin_amdgcn_readfirstlane(kb * 64 + wave * 16) + khalf * 8;
    #pragma unroll
    for (int u = 0; u < 8; ++u) {
      int k = k0 + u;                          // scalar base + uniform-per-half offset
      int c = (int)((unsigned)k / 9u);
      int ij = k - c * 9;
      int soff = c * 3136 + (ij / 3) * 56 + (ij % 3) - 57;
      const char* pk = (const char*)in + (ptrdiff_t)soff * 4;
      float v = 0.f;
      if ((vm >> ij) & 1)
        v = *(const float*)(pk + vbase);
      av[u] = v;
    }
  };

  auto loadB = [&](bf16x8 (&bq)[2][4], int kb) {   // [ks][fn], 8x global dwordx4
    #pragma unroll
    for (int ks = 0; ks < 2; ++ks)
      #pragma unroll
      for (int fn = 0; fn < 4; ++fn) {
        int ct = wave * 4 + fn;
        bq[ks][fn] = __builtin_bit_cast(bf16x8, *(const short8*)(
            (const char*)qw + ((size_t)((ct * 18 + kb) * 2 + ks) * 64 + lane) * 16));
      }
  };

  auto lmax_store = [&](float (&av)[8], int kb) {
    float lm = 0.f;
    #pragma unroll
    for (int u = 0; u < 8; ++u) lm = fmaxf(lm, fabsf(av[u]));
    lm = fmaxf(lm, __shfl_xor(lm, 32));          // merge the two 8-k halves of this row
    if (lane < 32) pmax[kb & 3][wave][prow] = lm;
  };

  auto quantWrite = [&](float (&av)[8], int kb) {  // -> As[kb&3], reads pmax[kb&3]
    const float* pb = &pmax[kb & 3][0][prow];
    float ma = fmaxf(fmaxf(pb[0], pb[32]), fmaxf(pb[64], pb[96]));
    short8 aq = (short8)0;
    if (ma > 0.f) {
      int e = (int)((__builtin_bit_cast(unsigned, ma) >> 23) & 0xffu) - 127;
      if (e < -126) e = -126;
      float inv = make_pow2(6 - e);
      float s   = make_pow2(e - 6);
      #pragma unroll
      for (int u = 0; u < 8; ++u) {
        float r = fminf(rintf(av[u] * inv), 127.f);  // lower clamp never binds
        float q = r * s;
        aq[u] = (short)(unsigned short)(__builtin_bit_cast(unsigned, q) >> 16);
      }
    }
    char* arow = (char*)As[kb & 3] + prow * 128;
    *(short8*)(arow + ((wave * 32 + khalf * 16) ^ ((prow & 7) << 4))) = aq;
  };

  auto mfmaBlk = [&](bf16x8 (&bq)[2][4], int kb) {  // reads As[kb&3]
    const char* abase = (const char*)As[kb & 3];
    __builtin_amdgcn_s_setprio(1);
    #pragma unroll
    for (int ks = 0; ks < 2; ++ks) {
      const int kbyte = (ks * 64 + lk) ^ swz;
      #pragma unroll
      for (int fm = 0; fm < 2; ++fm) {
        bf16x8 af = __builtin_bit_cast(bf16x8,
            *(const short8*)(abase + (fm * 16 + lr) * 128 + kbyte));
        #pragma unroll
        for (int fn = 0; fn < 4; ++fn)
          acc[fm][fn] = __builtin_amdgcn_mfma_f32_16x16x32_bf16(bq[ks][fn], af, acc[fm][fn], 0, 0, 0);
      }
    }
    __builtin_amdgcn_s_setprio(0);
  };

  // Superphase: one barrier per 2 kb; bq double-buffered (r8 schedule).
  auto superp = [&](int kb, float (&q0)[8], float (&q1)[8],
                    float (&g0)[8], float (&g1)[8]) {
    barrier_lgkm();                // As[kb&3],[kb+1&3] + pmax[(kb+2)&3],[(kb+3)&3] visible
    bf16x8 bq[2][4], bq2[2][4];
    loadB(bq, kb);
    if (kb + 2 < 18) { quantWrite(q0, kb + 2); quantWrite(q1, kb + 3); }
    if (kb + 4 < 18) { gather(g0, kb + 4); gather(g1, kb + 5); }
    loadB(bq2, kb + 1);            // covered by mfma(kb)
    mfmaBlk(bq, kb);
    if (kb + 4 < 18) { lmax_store(g0, kb + 4); lmax_store(g1, kb + 5); }
    mfmaBlk(bq2, kb + 1);
  };

  float gA[8], gB[8], gC[8], gD[8];

  // ---- prologue: fill pmax 0..3 and As 0,1 ----
  gather(gA, 0); gather(gB, 1); gather(gC, 2); gather(gD, 3);
  lmax_store(gA, 0); lmax_store(gB, 1); lmax_store(gC, 2); lmax_store(gD, 3);
  barrier_lgkm();                  // pmax 0..3 visible
  quantWrite(gA, 0); quantWrite(gB, 1);   // As0, As1  (gA,gB free)

  #pragma unroll 1
  for (int kb = 0; kb < 16; kb += 4) {
    superp(kb,     gC, gD, gA, gB);   // quant kb+2,kb+3; gather kb+4,kb+5
    superp(kb + 2, gA, gB, gC, gD);
  }
  superp(16, gC, gD, gA, gB);         // mfma 16,17 only (guards skip the rest)

  // ---- epilogue: D[co][pix]; 3136 % 32 == 0 so the 32-row tile is one image ----
  const unsigned ni = (mt * 32u) / 3136u;
  const unsigned pp0 = mt * 32u - ni * 3136u;
  float* obase = out + (size_t)ni * 802816u + pp0;
  const int cg = (lane >> 4) << 2;
  #pragma unroll
  for (int fn = 0; fn < 4; ++fn) {
    floatx4 bv = *(const floatx4*)&bias[wave * 64 + fn * 16 + cg];
    #pragma unroll
    for (int r = 0; r < 4; ++r) {
      int co = wave * 64 + fn * 16 + cg + r;
      float* orow = obase + (size_t)co * 3136u;
      #pragma unroll
      for (int fm = 0; fm < 2; ++fm)
        orow[fm * 16 + lr] = acc[fm][fn][r] + bv[r];
    }
  }
}

extern "C" void kernel_launch(void* const* d_in, const int* in_sizes, int n_in,
                              void* d_out, int out_size, void* d_ws, size_t ws_size,
                              hipStream_t stream) {
  const float* in   = (const float*)d_in[0];
  const float* w    = (const float*)d_in[1];
  const float* bias = (const float*)d_in[2];
  float* out = (float*)d_out;
  unsigned short* qw = (unsigned short*)d_ws;   // 16*18*1024 ushort = 589824 B

  quant_w_kernel<<<288, 64, 0, stream>>>(w, qw);
  conv_bfp_kernel<<<3136, 256, 0, stream>>>(in, qw, bias, out);
}